// Round 3
// baseline (569.348 us; speedup 1.0000x reference)
//
#include <hip/hip_runtime.h>
#include <hip/hip_bf16.h>
#include <stdint.h>

// Problem constants
#define N_ROWS 8192
#define IN_F   4096
#define OUT_F  4096
#define R_LORA 16
#define KP     4160   // padded K: 4096 data + col 4096 = bias-1.0 trick + zeros to /64

typedef __bf16 bf16_t;
typedef __attribute__((ext_vector_type(8))) __bf16 bf16x8;
typedef __attribute__((ext_vector_type(4))) __bf16 bf16x4;
typedef __attribute__((ext_vector_type(4))) float  f32x4;
typedef __attribute__((ext_vector_type(16))) float f32x16;

// ---------------------------------------------------------------------------
// async global->LDS, 16B per lane. LDS dest must be wave_base + lane*16.
// Per-lane SOURCE address is free-form (gather) — only the dest is constrained.
__device__ __forceinline__ void load16_lds(const bf16_t* g, bf16_t* l) {
    auto gp = (const __attribute__((address_space(1))) void*)g;
    auto lp = (__attribute__((address_space(3))) void*)(uint32_t)(uintptr_t)l;
    __builtin_amdgcn_global_load_lds(gp, lp, 16, 0, 0);
}

// ---------------------------------------------------------------------------
// Fused prep: blocks [0,2048) build Aw (4 rows each); blocks [2048,3072)
// build Bw (4 o-rows each). Unchanged (no counters for it yet — it will
// surface in top-5 once gemm drops below ~245 us, then gets diagnosed).
#define PREPA_BLOCKS 2048

__global__ __launch_bounds__(256) void prep_fused(const float* __restrict__ x,
                                                  const float* __restrict__ W,
                                                  const float* __restrict__ bias,
                                                  const float* __restrict__ lA,
                                                  const float* __restrict__ lB,
                                                  bf16_t* __restrict__ Aw,
                                                  bf16_t* __restrict__ Bw) {
    int b = blockIdx.x;
    int t = threadIdx.x;
    if (b < PREPA_BLOCKS) {
        int row0 = b * 4;
        for (int rr = 0; rr < 4; ++rr) {
            int row = row0 + rr;
            const float4* xr = (const float4*)(x + (size_t)row * IN_F);
            bf16_t* ar = Aw + (size_t)row * KP;
            for (int s = t; s < 512; s += 256) {
                float4 f0 = xr[2 * s];
                float4 f1 = xr[2 * s + 1];
                bf16x8 v;
                v[0] = (bf16_t)f0.x; v[1] = (bf16_t)f0.y;
                v[2] = (bf16_t)f0.z; v[3] = (bf16_t)f0.w;
                v[4] = (bf16_t)f1.x; v[5] = (bf16_t)f1.y;
                v[6] = (bf16_t)f1.z; v[7] = (bf16_t)f1.w;
                *(bf16x8*)(ar + s * 8) = v;
            }
            if (t < 64) ar[IN_F + t] = (t == 0) ? (bf16_t)1.0f : (bf16_t)0.0f;
        }
    } else {
        int o0 = (b - PREPA_BLOCKS) * 4;
        float bl[4][R_LORA];
        for (int oo = 0; oo < 4; ++oo)
            for (int r = 0; r < R_LORA; ++r)
                bl[oo][r] = 2.0f * lB[(o0 + oo) * R_LORA + r];

        for (int j = 0; j < IN_F / (256 * 4); ++j) {   // 4 iterations
            int i4 = (j * 256 + t) * 4;
            f32x4 acc[4];
            for (int oo = 0; oo < 4; ++oo) {
                float4 w = *(const float4*)(W + (size_t)(o0 + oo) * IN_F + i4);
                acc[oo] = (f32x4){w.x, w.y, w.z, w.w};
            }
            for (int r = 0; r < R_LORA; ++r) {
                float4 a = *(const float4*)(lA + (size_t)r * IN_F + i4);
                for (int oo = 0; oo < 4; ++oo) {
                    acc[oo][0] += bl[oo][r] * a.x;
                    acc[oo][1] += bl[oo][r] * a.y;
                    acc[oo][2] += bl[oo][r] * a.z;
                    acc[oo][3] += bl[oo][r] * a.w;
                }
            }
            for (int oo = 0; oo < 4; ++oo) {
                bf16x4 v;
                v[0] = (bf16_t)acc[oo][0]; v[1] = (bf16_t)acc[oo][1];
                v[2] = (bf16_t)acc[oo][2]; v[3] = (bf16_t)acc[oo][3];
                *(bf16x4*)(Bw + (size_t)(o0 + oo) * KP + i4) = v;
            }
        }
        {   // pad columns: 4 rows x 64 cols = 256 slots, one per thread
            int oo = t >> 6;
            int c  = IN_F + (t & 63);
            float v = (c == IN_F) ? bias[o0 + oo] : 0.0f;
            Bw[(size_t)(o0 + oo) * KP + c] = (bf16_t)v;
        }
    }
}

// ---------------------------------------------------------------------------
// NT bf16 GEMM: C[8192x4096] = Aw[8192xKP] * Bw[4096xKP]^T  (fp32 out)
//
// 256x256 tile, BK=64, 512 thr = 8 waves (2x4); per-wave output 128x64.
// m201-style 4-phase lockstep schedule (T3+T4+T5):
//
// per K-tile kt (read buf[cur], stage kt+1 -> buf[nb]):
//   stage ALL 8 gloads of kt+1          // after tile-entry barrier -> safe
//   s_waitcnt vmcnt(8)                  // kt's 8 landed; kt+1's 8 stay flying
//   s_barrier                           // publish kt to all waves
//   P0: read A0sub(8)+B0sub(4) -> 8 MFMA (quadrant 0,0) -> barrier
//   P1: read A1sub(8), reuse B0 -> 8 MFMA (1,0)          -> barrier
//   P2: read B1sub(4), reuse A1 -> 8 MFMA (1,1)          -> barrier
//   P3: read A0sub(8), reuse B1 -> 8 MFMA (0,1)          -> barrier (tile end)
//
// Why phases+barriers: R2's coarse region let all 8 waves burst-read LDS
// then burst-MFMA (bimodal, 43% MfmaUtil). Phase barriers pace LDS and MFMA
// pipes to alternate at ~500-cycle granularity; the 2 waves/SIMD interleave
// inside each MFMA window. vmcnt is counted (8) — the wait targets loads
// issued a full tile (~3300 cyc) earlier: non-blocking in steady state.
// Race audit: stage writes buf[nb] only after the tile-end barrier that
// retires all reads of buf[nb] (kt-1's reads); publish = own-vmcnt+barrier
// per wave => union of all waves' kt loads visible; compiler "memory" fence
// before tile-end barrier pins P3's ds_reads above the next stage.
#define BM 256
#define BN 256
#define BK 64
#define NT (KP / BK)    // 65

__global__ __launch_bounds__(512, 2) void gemm_bt(const bf16_t* __restrict__ A,
                                                  const bf16_t* __restrict__ B,
                                                  float* __restrict__ C) {
    __shared__ __align__(16) bf16_t lds[2][2][BM * BK];   // 128 KiB

    int bid = blockIdx.x;
    // XCD-aware bijective swizzle (512 blocks % 8 == 0)
    int swz = (bid & 7) * 64 + (bid >> 3);
    int bm  = swz & 31;              // 8192/256 = 32 row tiles
    int bn  = swz >> 5;              // 4096/256 = 16 col tiles
    int rowBase = bm * BM;
    int colBase = bn * BN;

    const int t    = threadIdx.x;
    const int lane = t & 63;
    const int wave = t >> 6;
    const int l31  = lane & 31;
    const int lhi  = lane >> 5;
    const int l7   = lane & 7;
    const int wr   = wave >> 2;      // 0..1: rows [wr*128, +128)
    const int wc   = wave & 3;       // 0..3: cols [wc*64, +64)

    // staging: chunk c = s*512 + t in [0,2048): r = c>>3 (256 rows), p = c&7.
    // LDS dest linear (required by global_load_lds); swizzle in SOURCE chunk.
    uint32_t srcA[4], srcB[4];
#pragma unroll
    for (int s = 0; s < 4; ++s) {
        int c = s * 512 + t;
        int r = c >> 3, p = c & 7;
        uint32_t off = (uint32_t)(r * KP + ((p ^ (r & 7)) << 3));
        srcA[s] = (uint32_t)(rowBase * KP) + off;
        srcB[s] = (uint32_t)(colBase * KP) + off;
    }

    auto stage = [&](int bsel, int k0) {   // 8 gload_lds per thread
#pragma unroll
        for (int s = 0; s < 4; ++s)
            load16_lds(A + srcA[s] + k0, &lds[bsel][0][(s * 512 + t) * 8]);
#pragma unroll
        for (int s = 0; s < 4; ++s)
            load16_lds(B + srcB[s] + k0, &lds[bsel][1][(s * 512 + t) * 8]);
    };

    f32x16 acc[4][2];
#pragma unroll
    for (int rf = 0; rf < 4; ++rf)
#pragma unroll
        for (int cf = 0; cf < 2; ++cf)
#pragma unroll
            for (int r = 0; r < 16; ++r) acc[rf][cf][r] = 0.f;

    bf16x8 af[2][4];   // A-subtile: 2 frag-rows x 4 k-steps
    bf16x8 bfr[4];     // B-subtile: 4 k-steps

#define READ_A(qr)                                                             \
    do {                                                                       \
        _Pragma("unroll")                                                      \
        for (int rf2 = 0; rf2 < 2; ++rf2)                                      \
            _Pragma("unroll")                                                  \
            for (int ks = 0; ks < 4; ++ks) {                                   \
                int row = wr * 128 + (qr) * 64 + rf2 * 32 + l31;               \
                int pos = ((((ks << 1) | lhi)) ^ l7) << 3;                     \
                af[rf2][ks] = *(const bf16x8*)&Ab[row * BK + pos];             \
            }                                                                  \
    } while (0)

#define READ_B(qc)                                                             \
    do {                                                                       \
        _Pragma("unroll")                                                      \
        for (int ks = 0; ks < 4; ++ks) {                                       \
            int col = wc * 64 + (qc) * 32 + l31;                               \
            int pos = ((((ks << 1) | lhi)) ^ l7) << 3;                         \
            bfr[ks] = *(const bf16x8*)&Bb[col * BK + pos];                     \
        }                                                                      \
    } while (0)

#define MMA(qr, qc)                                                            \
    do {                                                                       \
        __builtin_amdgcn_s_setprio(1);                                         \
        _Pragma("unroll")                                                      \
        for (int ks = 0; ks < 4; ++ks)                                         \
            _Pragma("unroll")                                                  \
            for (int rf2 = 0; rf2 < 2; ++rf2)                                  \
                acc[(qr) * 2 + rf2][qc] =                                      \
                    __builtin_amdgcn_mfma_f32_32x32x16_bf16(                   \
                        af[rf2][ks], bfr[ks], acc[(qr) * 2 + rf2][qc], 0, 0, 0);\
        __builtin_amdgcn_s_setprio(0);                                         \
    } while (0)

    // prologue: tile 0 -> buf 0
    stage(0, 0);

    for (int kt = 0; kt < NT; ++kt) {
        const int cur = kt & 1;
        const int nb  = cur ^ 1;
        const bf16_t* Ab = &lds[cur][0][0];
        const bf16_t* Bb = &lds[cur][1][0];

        // tile-entry: buf[nb] reads retired by previous tile-end barrier
        if (kt + 1 < NT) {
            stage(nb, (kt + 1) * BK);                        // 8 loads kt+1
            asm volatile("s_waitcnt vmcnt(8)" ::: "memory"); // kt landed
        } else {
            asm volatile("s_waitcnt vmcnt(0)" ::: "memory"); // stale drain
        }
        __builtin_amdgcn_s_barrier();                        // publish kt

        READ_A(0); READ_B(0); MMA(0, 0);
        __builtin_amdgcn_s_barrier();
        READ_A(1);            MMA(1, 0);
        __builtin_amdgcn_s_barrier();
        READ_B(1);            MMA(1, 1);
        __builtin_amdgcn_s_barrier();
        READ_A(0);            MMA(0, 1);
        asm volatile("" ::: "memory");     // pin P3 reads above tile-end bar
        __builtin_amdgcn_s_barrier();      // tile end: buf[cur] reads retired
    }
#undef READ_A
#undef READ_B
#undef MMA

    // epilogue: C/D layout col=l&31, row=(reg&3)+8*(reg>>2)+4*(l>>5)
#pragma unroll
    for (int rf = 0; rf < 4; ++rf) {
        int rB = rowBase + wr * 128 + rf * 32 + 4 * lhi;
#pragma unroll
        for (int cf = 0; cf < 2; ++cf) {
            int col = colBase + wc * 64 + cf * 32 + l31;
#pragma unroll
            for (int reg = 0; reg < 16; ++reg) {
                int row = rB + (reg & 3) + 8 * (reg >> 2);
                C[(size_t)row * OUT_F + col] = acc[rf][cf][reg];
            }
        }
    }
}

// ---------------------------------------------------------------------------
extern "C" void kernel_launch(void* const* d_in, const int* in_sizes, int n_in,
                              void* d_out, int out_size, void* d_ws, size_t ws_size,
                              hipStream_t stream) {
    const float* x  = (const float*)d_in[0];   // (8192, 4096)
    const float* W  = (const float*)d_in[1];   // (4096, 4096)
    const float* b  = (const float*)d_in[2];   // (4096,)
    const float* lA = (const float*)d_in[3];   // (16, 4096)
    const float* lB = (const float*)d_in[4];   // (4096, 16)
    float* out = (float*)d_out;                // (8192, 4096) fp32

    // workspace layout: Aw (8192 x 4160 bf16), Bw (4096 x 4160 bf16) ~102.3 MB
    bf16_t* Aw = (bf16_t*)d_ws;
    bf16_t* Bw = Aw + (size_t)N_ROWS * KP;

    prep_fused<<<PREPA_BLOCKS + OUT_F / 4, 256, 0, stream>>>(x, W, b, lA, lB, Aw, Bw);
    gemm_bt<<<(N_ROWS / BM) * (OUT_F / BN), 512, 0, stream>>>(Aw, Bw, out);
}

// Round 4
// 542.662 us; speedup vs baseline: 1.0492x; 1.0492x over previous
//
#include <hip/hip_runtime.h>
#include <hip/hip_bf16.h>
#include <stdint.h>

// Problem constants
#define N_ROWS 8192
#define IN_F   4096
#define OUT_F  4096
#define R_LORA 16
#define KP     4160   // padded K: 4096 data + col 4096 = bias-1.0 trick + zeros to /64

typedef __bf16 bf16_t;
typedef __attribute__((ext_vector_type(8))) __bf16 bf16x8;
typedef __attribute__((ext_vector_type(4))) __bf16 bf16x4;
typedef __attribute__((ext_vector_type(4))) float  f32x4;
typedef __attribute__((ext_vector_type(16))) float f32x16;

// ---------------------------------------------------------------------------
// async global->LDS, 16B per lane. LDS dest must be wave_base + lane*16.
// Per-lane SOURCE address is free-form (gather) — only the dest is constrained.
__device__ __forceinline__ void load16_lds(const bf16_t* g, bf16_t* l) {
    auto gp = (const __attribute__((address_space(1))) void*)g;
    auto lp = (__attribute__((address_space(3))) void*)(uint32_t)(uintptr_t)l;
    __builtin_amdgcn_global_load_lds(gp, lp, 16, 0, 0);
}

// ---------------------------------------------------------------------------
// Fused prep: blocks [0,2048) build Aw (4 rows each); blocks [2048,3072)
// build Bw (4 o-rows each). Unchanged: ~243 us vs ~48 us streaming roofline;
// it becomes the top-5 dispatch (and gets counters) once gemm drops below it.
#define PREPA_BLOCKS 2048

__global__ __launch_bounds__(256) void prep_fused(const float* __restrict__ x,
                                                  const float* __restrict__ W,
                                                  const float* __restrict__ bias,
                                                  const float* __restrict__ lA,
                                                  const float* __restrict__ lB,
                                                  bf16_t* __restrict__ Aw,
                                                  bf16_t* __restrict__ Bw) {
    int b = blockIdx.x;
    int t = threadIdx.x;
    if (b < PREPA_BLOCKS) {
        int row0 = b * 4;
        for (int rr = 0; rr < 4; ++rr) {
            int row = row0 + rr;
            const float4* xr = (const float4*)(x + (size_t)row * IN_F);
            bf16_t* ar = Aw + (size_t)row * KP;
            for (int s = t; s < 512; s += 256) {
                float4 f0 = xr[2 * s];
                float4 f1 = xr[2 * s + 1];
                bf16x8 v;
                v[0] = (bf16_t)f0.x; v[1] = (bf16_t)f0.y;
                v[2] = (bf16_t)f0.z; v[3] = (bf16_t)f0.w;
                v[4] = (bf16_t)f1.x; v[5] = (bf16_t)f1.y;
                v[6] = (bf16_t)f1.z; v[7] = (bf16_t)f1.w;
                *(bf16x8*)(ar + s * 8) = v;
            }
            if (t < 64) ar[IN_F + t] = (t == 0) ? (bf16_t)1.0f : (bf16_t)0.0f;
        }
    } else {
        int o0 = (b - PREPA_BLOCKS) * 4;
        float bl[4][R_LORA];
        for (int oo = 0; oo < 4; ++oo)
            for (int r = 0; r < R_LORA; ++r)
                bl[oo][r] = 2.0f * lB[(o0 + oo) * R_LORA + r];

        for (int j = 0; j < IN_F / (256 * 4); ++j) {   // 4 iterations
            int i4 = (j * 256 + t) * 4;
            f32x4 acc[4];
            for (int oo = 0; oo < 4; ++oo) {
                float4 w = *(const float4*)(W + (size_t)(o0 + oo) * IN_F + i4);
                acc[oo] = (f32x4){w.x, w.y, w.z, w.w};
            }
            for (int r = 0; r < R_LORA; ++r) {
                float4 a = *(const float4*)(lA + (size_t)r * IN_F + i4);
                for (int oo = 0; oo < 4; ++oo) {
                    acc[oo][0] += bl[oo][r] * a.x;
                    acc[oo][1] += bl[oo][r] * a.y;
                    acc[oo][2] += bl[oo][r] * a.z;
                    acc[oo][3] += bl[oo][r] * a.w;
                }
            }
            for (int oo = 0; oo < 4; ++oo) {
                bf16x4 v;
                v[0] = (bf16_t)acc[oo][0]; v[1] = (bf16_t)acc[oo][1];
                v[2] = (bf16_t)acc[oo][2]; v[3] = (bf16_t)acc[oo][3];
                *(bf16x4*)(Bw + (size_t)(o0 + oo) * KP + i4) = v;
            }
        }
        {   // pad columns: 4 rows x 64 cols = 256 slots, one per thread
            int oo = t >> 6;
            int c  = IN_F + (t & 63);
            float v = (c == IN_F) ? bias[o0 + oo] : 0.0f;
            Bw[(size_t)(o0 + oo) * KP + c] = (bf16_t)v;
        }
    }
}

// ---------------------------------------------------------------------------
// NT bf16 GEMM: C[8192x4096] = Aw[8192xKP] * Bw[4096xKP]^T  (fp32 out)
//
// Structure = R2 (best so far: 296 us, 2 barriers + counted vmcnt(8)/tile).
// ONLY change vs R2: the LDS slot swizzle.
//
// Conflict diagnosis (R0-R3 all showed exactly 4.0 SQ_LDS_BANK_CONFLICT per
// ds_read_b128): old slot class  p = ck ^ (row&7)  ignores row bits 3-4, so
// lanes {i,i+8,i+16,i+24} of a b128 read (same l7, rows 8 apart) hit the
// same 16B slot class in different rows -> 4-way bank conflict -> reads cost
// ~2400 cyc/CU/tile > 2048 cyc MFMA floor -> LDS-read-bound at 43% MfmaUtil.
//
// New slot class:  p(row,ck) = ck ^ (row&7) ^ (2*((row>>3)&3))
//  - bijective in ck per row (pure XOR)            -> staging stays 1:1
//  - aligned consecutive-8 lanes: 8 distinct slots (row&7 varies 0..7)
//  - stride-8 lanes {i,i+8,..,i+56}: plane ck gives (c^i)^{0,2,4,6} (4
//    distinct, even offsets), plane ck^1 gives the same set ^1 -> disjoint
//    -> all 8 distinct. Conflict-free under both plausible lane groupings.
// Read side cost unchanged: per-lane constant lsw = l7 ^ 2*(l31>>3), since
// frag row = (32-aligned base) + l31 gives row&7 = l7, (row>>3)&3 = l31>>3.
#define BM 256
#define BN 256
#define BK 64
#define NT (KP / BK)    // 65

__global__ __launch_bounds__(512, 2) void gemm_bt(const bf16_t* __restrict__ A,
                                                  const bf16_t* __restrict__ B,
                                                  float* __restrict__ C) {
    __shared__ __align__(16) bf16_t lds[2][2][BM * BK];   // 128 KiB

    int bid = blockIdx.x;
    // XCD-aware bijective swizzle (512 blocks % 8 == 0)
    int swz = (bid & 7) * 64 + (bid >> 3);
    int bm  = swz & 31;              // 8192/256 = 32 row tiles
    int bn  = swz >> 5;              // 4096/256 = 16 col tiles
    int rowBase = bm * BM;
    int colBase = bn * BN;

    const int t    = threadIdx.x;
    const int lane = t & 63;
    const int wave = t >> 6;
    const int l31  = lane & 31;
    const int lhi  = lane >> 5;
    const int l7   = lane & 7;
    const int lsw  = l7 ^ (2 * (l31 >> 3));   // read-side swizzle constant
    const int wr   = wave >> 2;      // 0..1: rows [wr*128, +128)
    const int wc   = wave & 3;       // 0..3: cols [wc*64, +64)

    // per-fragment LDS element offsets (before the per-ks pos term)
    int rowOffA[4], colOffB[2];
#pragma unroll
    for (int rf = 0; rf < 4; ++rf) rowOffA[rf] = (wr * 128 + rf * 32 + l31) * BK;
#pragma unroll
    for (int cf = 0; cf < 2; ++cf) colOffB[cf] = (wc * 64 + cf * 32 + l31) * BK;

    // staging: chunk c = s*512 + t in [0,2048): r = c>>3 (256 rows), p = c&7.
    // LDS dest linear (required by global_load_lds); swizzle in SOURCE chunk:
    // slot p of row r receives global chunk  p ^ (r&7) ^ (2*((r>>3)&3)).
    uint32_t srcA[4], srcB[4];
#pragma unroll
    for (int s = 0; s < 4; ++s) {
        int c = s * 512 + t;
        int r = c >> 3, p = c & 7;
        int ck = p ^ (r & 7) ^ (2 * ((r >> 3) & 3));
        uint32_t off = (uint32_t)(r * KP + (ck << 3));
        srcA[s] = (uint32_t)(rowBase * KP) + off;
        srcB[s] = (uint32_t)(colBase * KP) + off;
    }

    auto stage = [&](int bsel, int k0) {   // 8 gload_lds per thread
#pragma unroll
        for (int s = 0; s < 4; ++s)
            load16_lds(A + srcA[s] + k0, &lds[bsel][0][(s * 512 + t) * 8]);
#pragma unroll
        for (int s = 0; s < 4; ++s)
            load16_lds(B + srcB[s] + k0, &lds[bsel][1][(s * 512 + t) * 8]);
    };

    f32x16 acc[4][2];
#pragma unroll
    for (int rf = 0; rf < 4; ++rf)
#pragma unroll
        for (int cf = 0; cf < 2; ++cf)
#pragma unroll
            for (int r = 0; r < 16; ++r) acc[rf][cf][r] = 0.f;

#define COMPUTE(bsel)                                                          \
    do {                                                                       \
        const bf16_t* Ab = &lds[bsel][0][0];                                   \
        const bf16_t* Bb = &lds[bsel][1][0];                                   \
        _Pragma("unroll")                                                      \
        for (int ks = 0; ks < 4; ++ks) {                                       \
            int pos = ((((ks << 1) | lhi)) ^ lsw) << 3;                        \
            bf16x8 af[4], bf[2];                                               \
            _Pragma("unroll")                                                  \
            for (int rf = 0; rf < 4; ++rf)                                     \
                af[rf] = *(const bf16x8*)&Ab[rowOffA[rf] + pos];               \
            _Pragma("unroll")                                                  \
            for (int cf = 0; cf < 2; ++cf)                                     \
                bf[cf] = *(const bf16x8*)&Bb[colOffB[cf] + pos];               \
            __builtin_amdgcn_s_setprio(1);                                     \
            _Pragma("unroll")                                                  \
            for (int rf = 0; rf < 4; ++rf)                                     \
                _Pragma("unroll")                                              \
                for (int cf = 0; cf < 2; ++cf)                                 \
                    acc[rf][cf] = __builtin_amdgcn_mfma_f32_32x32x16_bf16(     \
                        af[rf], bf[cf], acc[rf][cf], 0, 0, 0);                 \
            __builtin_amdgcn_s_setprio(0);                                     \
        }                                                                      \
    } while (0)

    // prologue: tile 0 -> buf 0
    stage(0, 0);

    for (int kt = 0; kt < NT - 1; ++kt) {
        const int cur = kt & 1;
        const int nb  = cur ^ 1;
        __builtin_amdgcn_s_barrier();                  // reads of buf nb done
        stage(nb, (kt + 1) * BK);                      // tile kt+1 -> buf nb
        asm volatile("s_waitcnt vmcnt(8)" ::: "memory");   // tile kt landed
        __builtin_amdgcn_s_barrier();                  // ...for ALL waves
        COMPUTE(cur);
    }
    {   // tail: kt = NT-1 (= 64, buf 0); nothing left to issue
        __builtin_amdgcn_s_barrier();
        asm volatile("s_waitcnt vmcnt(0)" ::: "memory");
        __builtin_amdgcn_s_barrier();
        COMPUTE(0);
    }
#undef COMPUTE

    // epilogue: C/D layout col=l&31, row=(reg&3)+8*(reg>>2)+4*(l>>5)
#pragma unroll
    for (int rf = 0; rf < 4; ++rf) {
        int rB = rowBase + wr * 128 + rf * 32 + 4 * lhi;
#pragma unroll
        for (int cf = 0; cf < 2; ++cf) {
            int col = colBase + wc * 64 + cf * 32 + l31;
#pragma unroll
            for (int reg = 0; reg < 16; ++reg) {
                int row = rB + (reg & 3) + 8 * (reg >> 2);
                C[(size_t)row * OUT_F + col] = acc[rf][cf][reg];
            }
        }
    }
}

// ---------------------------------------------------------------------------
extern "C" void kernel_launch(void* const* d_in, const int* in_sizes, int n_in,
                              void* d_out, int out_size, void* d_ws, size_t ws_size,
                              hipStream_t stream) {
    const float* x  = (const float*)d_in[0];   // (8192, 4096)
    const float* W  = (const float*)d_in[1];   // (4096, 4096)
    const float* b  = (const float*)d_in[2];   // (4096,)
    const float* lA = (const float*)d_in[3];   // (16, 4096)
    const float* lB = (const float*)d_in[4];   // (4096, 16)
    float* out = (float*)d_out;                // (8192, 4096) fp32

    // workspace layout: Aw (8192 x 4160 bf16), Bw (4096 x 4160 bf16) ~102.3 MB
    bf16_t* Aw = (bf16_t*)d_ws;
    bf16_t* Bw = Aw + (size_t)N_ROWS * KP;

    prep_fused<<<PREPA_BLOCKS + OUT_F / 4, 256, 0, stream>>>(x, W, b, lA, lB, Aw, Bw);
    gemm_bt<<<(N_ROWS / BM) * (OUT_F / BN), 512, 0, stream>>>(Aw, Bw, out);
}